// Round 2
// baseline (139.349 us; speedup 1.0000x reference)
//
#include <hip/hip_runtime.h>
#include <math.h>

constexpr int B = 32, D = 32, T = 16384, N = 128;

// numpy pairwise_sum (n=32): 8 accumulators + ordered combine; inputs are
// the separately-rounded squares a_i = fl(v_i*v_i).
__device__ __forceinline__ float np_pairwise32_sq(const float* v) {
#pragma clang fp contract(off)
    float r[8];
    #pragma unroll
    for (int j = 0; j < 8; ++j) r[j] = v[j] * v[j];
    #pragma unroll
    for (int i = 8; i < 32; i += 8) {
        #pragma unroll
        for (int j = 0; j < 8; ++j) r[j] += v[i + j] * v[i + j];
    }
    return ((r[0] + r[1]) + (r[2] + r[3])) + ((r[4] + r[5]) + (r[6] + r[7]));
}

__global__ __launch_bounds__(256) void ve_kernel(
    const float* __restrict__ source,   // [B][D][T]
    const float* __restrict__ tokens,   // [D][N]
    float* __restrict__ out)            // [B][D][T]
{
#pragma clang fp contract(off)
    __shared__ float rn[N][D];      // normalized refs, np-bit-exact
    __shared__ float rf[N][D + 1];  // raw refs, +1 pad (gather bank conflicts)

    for (int i = threadIdx.x; i < N * D; i += 256) {
        int d = i >> 7, n = i & (N - 1);     // tokens[d*N + n]
        rf[n][d] = tokens[i];
    }
    __syncthreads();

    if (threadIdx.x < N) {
        int n = threadIdx.x;
        float tq[D];
        #pragma unroll
        for (int d = 0; d < D; ++d) tq[d] = rf[n][d];
        float nrm = sqrtf(np_pairwise32_sq(tq));   // IEEE sqrt (hip default)
        #pragma unroll
        for (int d = 0; d < D; ++d) rn[n][d] = tq[d] / nrm;  // IEEE div
    }
    __syncthreads();

    int gid = blockIdx.x * 256 + threadIdx.x;
    int b = gid >> 14, t = gid & (T - 1);

    const float* src = source + (size_t)b * D * T + t;
    float s[D];
    #pragma unroll
    for (int d = 0; d < D; ++d) s[d] = src[(size_t)d * T];

    float nrm = sqrtf(np_pairwise32_sq(s));
    float sn[D];
    #pragma unroll
    for (int d = 0; d < D; ++d) sn[d] = s[d] / nrm;

    // Top-4, branchless shift-insert; strict > keeps lower index on ties
    // (matches stable/jax tie semantics at the 4/5 boundary).
    float tv0 = -INFINITY, tv1 = -INFINITY, tv2 = -INFINITY, tv3 = -INFINITY;
    int ti0 = 0, ti1 = 0, ti2 = 0, ti3 = 0;

    for (int n = 0; n < N; ++n) {
        // numpy einsum (strided-d operands): sequential fold over d ascending,
        // each product and each add separately rounded. float4 LDS loads keep
        // the same math with 8x fewer ds_read ops.
        const float4* rw = reinterpret_cast<const float4*>(&rn[n][0]);
        float acc = 0.0f;
        #pragma unroll
        for (int k = 0; k < 8; ++k) {
            float4 q = rw[k];
            acc += sn[4 * k + 0] * q.x;
            acc += sn[4 * k + 1] * q.y;
            acc += sn[4 * k + 2] * q.z;
            acc += sn[4 * k + 3] * q.w;
        }

        bool c0 = acc > tv0, c1 = acc > tv1, c2 = acc > tv2, c3 = acc > tv3;
        float nv3 = c3 ? (c2 ? tv2 : acc) : tv3;  int ni3 = c3 ? (c2 ? ti2 : n) : ti3;
        float nv2 = c2 ? (c1 ? tv1 : acc) : tv2;  int ni2 = c2 ? (c1 ? ti1 : n) : ti2;
        float nv1 = c1 ? (c0 ? tv0 : acc) : tv1;  int ni1 = c1 ? (c0 ? ti0 : n) : ti1;
        float nv0 = c0 ? acc : tv0;               int ni0 = c0 ? n : ti0;
        tv0 = nv0; tv1 = nv1; tv2 = nv2; tv3 = nv3;
        ti0 = ni0; ti1 = ni1; ti2 = ni2; ti3 = ni3;
    }

    // mean over K in top-k order: ((g0+g1)+g2)+g3, then /4 (== *0.25 exactly)
    float* dst = out + (size_t)b * D * T + t;
    #pragma unroll
    for (int d = 0; d < D; ++d) {
        float sum = ((rf[ti0][d] + rf[ti1][d]) + rf[ti2][d]) + rf[ti3][d];
        dst[(size_t)d * T] = sum * 0.25f;
    }
}

extern "C" void kernel_launch(void* const* d_in, const int* in_sizes, int n_in,
                              void* d_out, int out_size, void* d_ws, size_t ws_size,
                              hipStream_t stream) {
    const float* source = (const float*)d_in[0];   // B*D*T fp32
    const float* tokens = (const float*)d_in[1];   // D*N   fp32
    float* out = (float*)d_out;

    dim3 grid((B * T) / 256), block(256);
    ve_kernel<<<grid, block, 0, stream>>>(source, tokens, out);
}